// Round 1
// baseline (598.297 us; speedup 1.0000x reference)
//
#include <hip/hip_runtime.h>
#include <math.h>

// Shapes (fixed): Na=32, La=32, B=64, Lb=32, Din=H=768.
// ws layout (floats): q[1024*768] k[2048*768] v[2048*768] ecls[32*768]
//                     iq[1024] ik[2048] C[1024*2048]  (~23.1 MiB)

// ---------------- GEMM: C = A @ W + bias;  A[M,768], W[768,768] row-major ----------------
__global__ __launch_bounds__(256) void gemm_bias_kernel(
    const float* __restrict__ A, const float* __restrict__ W,
    const float* __restrict__ bias, float* __restrict__ C, int M) {
  __shared__ float As[64][17];
  __shared__ float Ws[16][65];
  const int tid = threadIdx.x;
  const int tx = tid & 15, ty = tid >> 4;
  const int bn = blockIdx.x * 64, bm = blockIdx.y * 64;
  float acc[4][4] = {};
  for (int k0 = 0; k0 < 768; k0 += 16) {
    {
      int ar = tid >> 2, ak = (tid & 3) << 2;
      int gm = bm + ar;
      float4 a4 = make_float4(0.f, 0.f, 0.f, 0.f);
      if (gm < M) a4 = *(const float4*)(A + (size_t)gm * 768 + k0 + ak);
      As[ar][ak] = a4.x; As[ar][ak + 1] = a4.y; As[ar][ak + 2] = a4.z; As[ar][ak + 3] = a4.w;
      int wk = tid >> 4, wc = (tid & 15) << 2;
      float4 w4 = *(const float4*)(W + (size_t)(k0 + wk) * 768 + bn + wc);
      Ws[wk][wc] = w4.x; Ws[wk][wc + 1] = w4.y; Ws[wk][wc + 2] = w4.z; Ws[wk][wc + 3] = w4.w;
    }
    __syncthreads();
#pragma unroll
    for (int kk = 0; kk < 16; ++kk) {
      float ar4[4], wc4[4];
#pragma unroll
      for (int r = 0; r < 4; ++r) ar4[r] = As[ty * 4 + r][kk];
#pragma unroll
      for (int c = 0; c < 4; ++c) wc4[c] = Ws[kk][tx * 4 + c];
#pragma unroll
      for (int r = 0; r < 4; ++r)
#pragma unroll
        for (int c = 0; c < 4; ++c) acc[r][c] += ar4[r] * wc4[c];
    }
    __syncthreads();
  }
#pragma unroll
  for (int r = 0; r < 4; ++r) {
    int gm = bm + ty * 4 + r;
    if (gm >= M) continue;
#pragma unroll
    for (int c = 0; c < 4; ++c) {
      int gn = bn + tx * 4 + c;
      C[(size_t)gm * 768 + gn] = acc[r][c] + bias[gn];
    }
  }
}

// ---------------- inverse L2 row norms (wave per row) ----------------
__global__ __launch_bounds__(256) void rownorm_kernel(
    const float* __restrict__ X, float* __restrict__ inv, int M) {
  int row = blockIdx.x * 4 + (threadIdx.x >> 6);
  int lane = threadIdx.x & 63;
  if (row >= M) return;
  const float* x = X + (size_t)row * 768;
  float s = 0.f;
  for (int h = lane; h < 768; h += 64) { float v = x[h]; s += v * v; }
#pragma unroll
  for (int m = 1; m < 64; m <<= 1) s += __shfl_xor(s, m);
  if (lane == 0) inv[row] = 1.0f / fmaxf(sqrtf(s), 1e-8f);
}

// ---------------- C = (q @ k^T) * iq * ik  -> [1024, 2048] ----------------
__global__ __launch_bounds__(256) void cos_gemm_kernel(
    const float* __restrict__ Q, const float* __restrict__ K,
    const float* __restrict__ iq, const float* __restrict__ ik,
    float* __restrict__ C) {
  __shared__ float As[64][17];
  __shared__ float Bs[64][17];
  const int tid = threadIdx.x;
  const int tx = tid & 15, ty = tid >> 4;
  const int bn = blockIdx.x * 64, bm = blockIdx.y * 64;
  float acc[4][4] = {};
  for (int k0 = 0; k0 < 768; k0 += 16) {
    {
      int r = tid >> 2, kk = (tid & 3) << 2;
      float4 a4 = *(const float4*)(Q + (size_t)(bm + r) * 768 + k0 + kk);
      As[r][kk] = a4.x; As[r][kk + 1] = a4.y; As[r][kk + 2] = a4.z; As[r][kk + 3] = a4.w;
      float4 b4 = *(const float4*)(K + (size_t)(bn + r) * 768 + k0 + kk);
      Bs[r][kk] = b4.x; Bs[r][kk + 1] = b4.y; Bs[r][kk + 2] = b4.z; Bs[r][kk + 3] = b4.w;
    }
    __syncthreads();
#pragma unroll
    for (int k2 = 0; k2 < 16; ++k2) {
      float a4r[4], b4c[4];
#pragma unroll
      for (int r2 = 0; r2 < 4; ++r2) a4r[r2] = As[ty * 4 + r2][k2];
#pragma unroll
      for (int c2 = 0; c2 < 4; ++c2) b4c[c2] = Bs[tx * 4 + c2][k2];
#pragma unroll
      for (int r2 = 0; r2 < 4; ++r2)
#pragma unroll
        for (int c2 = 0; c2 < 4; ++c2) acc[r2][c2] += a4r[r2] * b4c[c2];
    }
    __syncthreads();
  }
#pragma unroll
  for (int r2 = 0; r2 < 4; ++r2) {
    int m = bm + ty * 4 + r2;
    float sm = iq[m];
#pragma unroll
    for (int c2 = 0; c2 < 4; ++c2) {
      int n = bn + tx * 4 + c2;
      C[(size_t)m * 2048 + n] = acc[r2][c2] * sm * ik[n];
    }
  }
}

// ---------------- Sinkhorn per (a,b) 32x32 tile, in-place, + final row L2 norm ----------------
// thread t: row i = t>>3, cols j0..j0+3, j0 = (t&7)*4. Row lives in 8 consecutive lanes.
__global__ __launch_bounds__(256) void sinkhorn_kernel(float* __restrict__ C) {
  const int pair = blockIdx.x;
  const int a = pair >> 6, b = pair & 63;
  const int t = threadIdx.x;
  const int i = t >> 3, j0 = (t & 7) << 2;
  const int wave = t >> 6;
  float* base = C + (size_t)(a * 32) * 2048 + b * 32;
  __shared__ float colpart[4][32];
  float4 c4 = *(const float4*)(base + (size_t)i * 2048 + j0);
  float qv[4] = { expf(c4.x * 10.f), expf(c4.y * 10.f), expf(c4.z * 10.f), expf(c4.w * 10.f) };
  for (int it = 0; it < 10; ++it) {
    // row normalize (8 lanes own the full row -> pure shuffle)
    float rs = qv[0] + qv[1] + qv[2] + qv[3];
    rs += __shfl_xor(rs, 1); rs += __shfl_xor(rs, 2); rs += __shfl_xor(rs, 4);
    float rinv = 1.0f / rs;
#pragma unroll
    for (int u = 0; u < 4; ++u) qv[u] *= rinv;
    // column partials within wave (8 rows), then LDS combine across 4 waves
    float cp[4] = { qv[0], qv[1], qv[2], qv[3] };
#pragma unroll
    for (int m = 8; m < 64; m <<= 1) {
#pragma unroll
      for (int u = 0; u < 4; ++u) cp[u] += __shfl_xor(cp[u], m);
    }
    __syncthreads();   // previous iteration's colpart reads complete
    if ((t & 63) < 8) {
#pragma unroll
      for (int u = 0; u < 4; ++u) colpart[wave][j0 + u] = cp[u];
    }
    __syncthreads();
#pragma unroll
    for (int u = 0; u < 4; ++u) {
      float cs = colpart[0][j0 + u] + colpart[1][j0 + u] + colpart[2][j0 + u] + colpart[3][j0 + u];
      qv[u] /= cs;
    }
  }
  // final: L2 normalize rows (F.normalize dim=-1)
  float ss = qv[0] * qv[0] + qv[1] * qv[1] + qv[2] * qv[2] + qv[3] * qv[3];
  ss += __shfl_xor(ss, 1); ss += __shfl_xor(ss, 2); ss += __shfl_xor(ss, 4);
  float tinv = 1.0f / fmaxf(sqrtf(ss), 1e-12f);
  float4 o4 = make_float4(qv[0] * tinv, qv[1] * tinv, qv[2] * tinv, qv[3] * tinv);
  *(float4*)(base + (size_t)i * 2048 + j0) = o4;
}

// ---------------- Fused: attended = T@v + q -> LN1 -> softpool -> LN2 -> scores ----------------
// grid 2048 (pair), block 1024. Thread map: r = tid>>7 (0..7) owns rows {r, r+8, r+16, r+24};
// qx = tid&127 owns cols [6qx, 6qx+6). acc[4][6] registers hold the 32x768 attended tile.
__global__ __launch_bounds__(1024) void attn_pool_kernel(
    const float* __restrict__ T, const float* __restrict__ Vm, const float* __restrict__ Qm,
    const float* __restrict__ ecls, const float* __restrict__ entity_cls,
    const float* __restrict__ mention_cls,
    const float* __restrict__ ln1_g, const float* __restrict__ ln1_b,
    const float* __restrict__ Wsp, const float* __restrict__ bsp,
    const float* __restrict__ ln2_g, const float* __restrict__ ln2_b,
    float* __restrict__ out) {
  const int pair = blockIdx.x;
  const int a = pair >> 6, b = pair & 63;
  const int tid = threadIdx.x;
  const int w = tid >> 6;       // wave 0..15
  const int r = tid >> 7;       // row-thread 0..7
  const int qx = tid & 127;     // col-thread 0..127

  __shared__ float Ts[32][33];
  __shared__ float smem[16 * 768];   // phase 1: v half-tile staging; phase 2: pool[8][768]
  __shared__ float red[16][8];
  __shared__ float svals[32];

  { // load T tile (post-sinkhorn layout [1024,2048])
    int i = tid >> 5, j = tid & 31;
    Ts[i][j] = T[(size_t)(a * 32 + i) * 2048 + b * 32 + j];
  }

  float acc[4][6];
#pragma unroll
  for (int ri = 0; ri < 4; ++ri) {
    const float* qrow = Qm + (size_t)(a * 32 + r + 8 * ri) * 768 + qx * 6;
#pragma unroll
    for (int c = 0; c < 6; ++c) acc[ri][c] = qrow[c];   // residual q
  }

  for (int ph = 0; ph < 2; ++ph) {
    const int jbase = ph * 16;
    __syncthreads();                       // Ts visible / previous-phase reads done
#pragma unroll
    for (int u = 0; u < 12; ++u) {         // stage 16 v-rows (48 KiB f32)
      int e = tid + u * 1024;
      int jj = e / 768, h2 = e - jj * 768;
      smem[e] = Vm[(size_t)(b * 32 + jbase + jj) * 768 + h2];
    }
    __syncthreads();
#pragma unroll
    for (int j = 0; j < 16; ++j) {
      float vv[6];
      const float* vrow = smem + j * 768 + qx * 6;
#pragma unroll
      for (int c = 0; c < 6; ++c) vv[c] = vrow[c];
#pragma unroll
      for (int ri = 0; ri < 4; ++ri) {
        float tj = Ts[r + 8 * ri][jbase + j];
#pragma unroll
        for (int c = 0; c < 6; ++c) acc[ri][c] += tj * vv[c];
      }
    }
  }

  // ---- LN1 per attended row ----
  float rsum[4], rsq[4];
#pragma unroll
  for (int ri = 0; ri < 4; ++ri) {
    float s = 0.f, s2 = 0.f;
#pragma unroll
    for (int c = 0; c < 6; ++c) { s += acc[ri][c]; s2 += acc[ri][c] * acc[ri][c]; }
    rsum[ri] = s; rsq[ri] = s2;
  }
#pragma unroll
  for (int m = 1; m < 64; m <<= 1) {
#pragma unroll
    for (int ri = 0; ri < 4; ++ri) { rsum[ri] += __shfl_xor(rsum[ri], m); rsq[ri] += __shfl_xor(rsq[ri], m); }
  }
  if ((tid & 63) == 0) {
#pragma unroll
    for (int ri = 0; ri < 4; ++ri) { red[w][ri] = rsum[ri]; red[w][4 + ri] = rsq[ri]; }
  }
  __syncthreads();
  float mean[4], rstd[4];
#pragma unroll
  for (int ri = 0; ri < 4; ++ri) {
    float s = red[2 * r][ri] + red[2 * r + 1][ri];
    float s2 = red[2 * r][4 + ri] + red[2 * r + 1][4 + ri];
    float m1 = s * (1.0f / 768.0f);
    float var = s2 * (1.0f / 768.0f) - m1 * m1;
    mean[ri] = m1; rstd[ri] = rsqrtf(var + 1e-5f);
  }
  float g1[6], b1[6], wspv[6];
#pragma unroll
  for (int c = 0; c < 6; ++c) {
    g1[c] = ln1_g[qx * 6 + c]; b1[c] = ln1_b[qx * 6 + c]; wspv[c] = Wsp[qx * 6 + c];
  }
#pragma unroll
  for (int ri = 0; ri < 4; ++ri)
#pragma unroll
    for (int c = 0; c < 6; ++c) acc[ri][c] = (acc[ri][c] - mean[ri]) * rstd[ri] * g1[c] + b1[c];

  // ---- s_i = attended_ln @ Wsp + bsp, softmax over rows ----
  float sp[4];
#pragma unroll
  for (int ri = 0; ri < 4; ++ri) {
    float s = 0.f;
#pragma unroll
    for (int c = 0; c < 6; ++c) s += acc[ri][c] * wspv[c];
    sp[ri] = s;
  }
#pragma unroll
  for (int m = 1; m < 64; m <<= 1) {
#pragma unroll
    for (int ri = 0; ri < 4; ++ri) sp[ri] += __shfl_xor(sp[ri], m);
  }
  __syncthreads();   // red reads above done before rewrite
  if ((tid & 63) == 0) {
#pragma unroll
    for (int ri = 0; ri < 4; ++ri) red[w][ri] = sp[ri];
  }
  __syncthreads();
  const float bsp0 = bsp[0];
  float sv[4];
#pragma unroll
  for (int ri = 0; ri < 4; ++ri) sv[ri] = red[2 * r][ri] + red[2 * r + 1][ri] + bsp0;
  if (qx == 0) {
#pragma unroll
    for (int ri = 0; ri < 4; ++ri) svals[r + 8 * ri] = sv[ri];
  }
  __syncthreads();
  float mx = -1e30f;
#pragma unroll
  for (int i2 = 0; i2 < 32; ++i2) mx = fmaxf(mx, svals[i2]);
  float se = 0.f;
#pragma unroll
  for (int i2 = 0; i2 < 32; ++i2) se += expf(svals[i2] - mx);
  const float sinv = 1.0f / se;
  float wv[4];
#pragma unroll
  for (int ri = 0; ri < 4; ++ri) wv[ri] = expf(sv[ri] - mx) * sinv;

  // ---- pooled[h] = sum_i w_i * attended_ln[i][h] ----
  float pol[6];
#pragma unroll
  for (int c = 0; c < 6; ++c) {
    float s = 0.f;
#pragma unroll
    for (int ri = 0; ri < 4; ++ri) s += wv[ri] * acc[ri][c];
    pol[c] = s;
  }
  __syncthreads();   // all v reads of smem long done; red reads done
#pragma unroll
  for (int c = 0; c < 6; ++c) smem[r * 768 + qx * 6 + c] = pol[c];
  __syncthreads();

  float pooled = 0.f, psum = 0.f, psq = 0.f;
  const int h2 = tid;
  if (tid < 768) {
#pragma unroll
    for (int r2 = 0; r2 < 8; ++r2) pooled += smem[r2 * 768 + h2];
    psum = pooled; psq = pooled * pooled;
  }
#pragma unroll
  for (int m = 1; m < 64; m <<= 1) { psum += __shfl_xor(psum, m); psq += __shfl_xor(psq, m); }
  if ((tid & 63) == 0) { red[w][0] = psum; red[w][1] = psq; }
  __syncthreads();
  float s = 0.f, s2 = 0.f;
#pragma unroll
  for (int w2 = 0; w2 < 16; ++w2) { s += red[w2][0]; s2 += red[w2][1]; }
  const float m2 = s * (1.0f / 768.0f);
  const float var2 = s2 * (1.0f / 768.0f) - m2 * m2;
  const float rs2 = rsqrtf(var2 + 1e-5f);

  float totp = 0.f;
  if (tid < 768) {
    float ctx = (pooled - m2) * rs2 * ln2_g[h2] + ln2_b[h2];
    totp = ctx * ecls[(size_t)a * 768 + h2]
         + mention_cls[(size_t)b * 768 + h2] * entity_cls[(size_t)a * 768 + h2];
  }
  __syncthreads();   // red reads done before rewrite
#pragma unroll
  for (int m = 1; m < 64; m <<= 1) totp += __shfl_xor(totp, m);
  if ((tid & 63) == 0) red[w][0] = totp;
  __syncthreads();
  if (tid == 0) {
    float t2 = 0.f;
#pragma unroll
    for (int w2 = 0; w2 < 16; ++w2) t2 += red[w2][0];
    out[b * 32 + a] = 0.5f * t2;
  }
}

extern "C" void kernel_launch(void* const* d_in, const int* in_sizes, int n_in,
                              void* d_out, int out_size, void* d_ws, size_t ws_size,
                              hipStream_t stream) {
  const float* entity_cls     = (const float*)d_in[0];
  const float* entity_tokens  = (const float*)d_in[1];
  const float* mention_cls    = (const float*)d_in[2];
  const float* mention_tokens = (const float*)d_in[3];
  const float* Wq = (const float*)d_in[4];   const float* bq = (const float*)d_in[5];
  const float* Wk = (const float*)d_in[6];   const float* bk = (const float*)d_in[7];
  const float* Wv = (const float*)d_in[8];   const float* bv = (const float*)d_in[9];
  const float* ln1_g = (const float*)d_in[10]; const float* ln1_b = (const float*)d_in[11];
  const float* Wcls = (const float*)d_in[12];  const float* bcls = (const float*)d_in[13];
  const float* Wsp = (const float*)d_in[14];   const float* bsp = (const float*)d_in[15];
  const float* ln2_g = (const float*)d_in[16]; const float* ln2_b = (const float*)d_in[17];
  float* out = (float*)d_out;

  float* ws  = (float*)d_ws;
  float* q    = ws;                        // 1024*768
  float* k    = q + 1024 * 768;            // 2048*768
  float* v    = k + 2048 * 768;            // 2048*768
  float* ecls = v + 2048 * 768;            // 32*768
  float* iq   = ecls + 32 * 768;           // 1024
  float* ik   = iq + 1024;                 // 2048
  float* C    = ik + 2048;                 // 1024*2048 (becomes T in-place)

  dim3 blk(256);
  gemm_bias_kernel<<<dim3(12, 16), blk, 0, stream>>>(entity_tokens, Wq, bq, q, 1024);
  gemm_bias_kernel<<<dim3(12, 32), blk, 0, stream>>>(mention_tokens, Wk, bk, k, 2048);
  gemm_bias_kernel<<<dim3(12, 32), blk, 0, stream>>>(mention_tokens, Wv, bv, v, 2048);
  gemm_bias_kernel<<<dim3(12, 1),  blk, 0, stream>>>(entity_cls, Wcls, bcls, ecls, 32);
  rownorm_kernel<<<dim3(256), blk, 0, stream>>>(q, iq, 1024);
  rownorm_kernel<<<dim3(512), blk, 0, stream>>>(k, ik, 2048);
  cos_gemm_kernel<<<dim3(32, 16), blk, 0, stream>>>(q, k, iq, ik, C);
  sinkhorn_kernel<<<dim3(2048), blk, 0, stream>>>(C);
  attn_pool_kernel<<<dim3(2048), dim3(1024), 0, stream>>>(
      C, v, q, ecls, entity_cls, mention_cls,
      ln1_g, ln1_b, Wsp, bsp, ln2_g, ln2_b, out);
}

// Round 2
// 386.731 us; speedup vs baseline: 1.5471x; 1.5471x over previous
//
#include <hip/hip_runtime.h>
#include <math.h>

// Shapes (fixed): Na=32, La=32, B=64, Lb=32, Din=H=768.

typedef __attribute__((ext_vector_type(8))) short bfrag8;   // 8 bf16 in 4 VGPRs
typedef __attribute__((ext_vector_type(4))) float f32x4;

__device__ __forceinline__ unsigned short f2bf(float x) {
  union { float f; unsigned u; } v; v.f = x;
  unsigned r = v.u + 0x7fffu + ((v.u >> 16) & 1u);
  return (unsigned short)(r >> 16);
}

// ---------------- f32 -> bf16 elementwise (n4 = n/4) ----------------
__global__ __launch_bounds__(256) void cvt_bf16_kernel(
    const float* __restrict__ in, unsigned short* __restrict__ out, int n4) {
  int i = blockIdx.x * 256 + threadIdx.x;
  if (i >= n4) return;
  float4 f = ((const float4*)in)[i];
  ushort4 o;
  o.x = f2bf(f.x); o.y = f2bf(f.y); o.z = f2bf(f.z); o.w = f2bf(f.w);
  ((ushort4*)out)[i] = o;
}

// ---------------- W[768][768] f32 -> WT[768][768] bf16 (transposed), 4 weights ----------------
__global__ __launch_bounds__(256) void transpose_cvt_kernel(
    const float* __restrict__ W0, const float* __restrict__ W1,
    const float* __restrict__ W2, const float* __restrict__ W3,
    unsigned short* __restrict__ O0, unsigned short* __restrict__ O1,
    unsigned short* __restrict__ O2, unsigned short* __restrict__ O3) {
  const int z = blockIdx.z;
  const float* W = (z == 0) ? W0 : (z == 1) ? W1 : (z == 2) ? W2 : W3;
  unsigned short* O = (z == 0) ? O0 : (z == 1) ? O1 : (z == 2) ? O2 : O3;
  __shared__ float t[32][33];
  const int bx = blockIdx.x * 32, by = blockIdx.y * 32; // bx: n (cols of W), by: k (rows)
  const int tx = threadIdx.x & 31, ty = threadIdx.x >> 5;
#pragma unroll
  for (int u = 0; u < 4; ++u) {
    int row = ty + u * 8;
    t[row][tx] = W[(size_t)(by + row) * 768 + bx + tx];
  }
  __syncthreads();
#pragma unroll
  for (int u = 0; u < 4; ++u) {
    int row = ty + u * 8;
    O[(size_t)(bx + row) * 768 + by + tx] = f2bf(t[tx][row]);
  }
}

// ---------------- bf16 MFMA GEMM: C[M][N] = A[M][768] @ B[N][768]^T ----------------
// MODE 0: +bias[n], write f32 Cf (+ optional bf16 Cb), ldc = N = 768
// MODE 1: scale by iq[m]*ik[n], write f32 Cf, ldc = 2048
// tile 128x128, 256 threads (4 waves), BK=64, mfma_f32_16x16x32_bf16, 4x4 subtiles/wave.
// LDS XOR swizzle on 16B chunks keeps both ds_write and ds_read at <=2-way conflicts.
template <int MODE>
__global__ __launch_bounds__(256) void mfma_gemm_kernel(
    const unsigned short* __restrict__ A,   // [M][768] bf16 row-major
    const unsigned short* __restrict__ B,   // [N][768] bf16 (n-major, k contiguous)
    const float* __restrict__ bias,
    const float* __restrict__ iq, const float* __restrict__ ik,
    float* __restrict__ Cf, unsigned short* __restrict__ Cb,
    int M, int ldc) {
  __shared__ unsigned short As[128 * 64];
  __shared__ unsigned short Bs[128 * 64];
  const int t = threadIdx.x;
  const int bn = blockIdx.x * 128, bm = blockIdx.y * 128;
  const int l = t & 63, w = t >> 6;
  const int wm = w & 1, wn = w >> 1;

  f32x4 acc[4][4];
#pragma unroll
  for (int mi = 0; mi < 4; ++mi)
#pragma unroll
    for (int nj = 0; nj < 4; ++nj) { f32x4 z = {0.f, 0.f, 0.f, 0.f}; acc[mi][nj] = z; }

  for (int k0 = 0; k0 < 768; k0 += 64) {
    __syncthreads();
#pragma unroll
    for (int u = 0; u < 4; ++u) {
      int c = t + u * 256;
      int row = c >> 3, kc = c & 7;
      int gm = bm + row; gm = gm < M ? gm : M - 1;
      int4 av = *(const int4*)(A + (size_t)gm * 768 + k0 + kc * 8);
      *(int4*)(As + row * 64 + ((kc ^ (row & 7)) * 8)) = av;
      int4 bv = *(const int4*)(B + (size_t)(bn + row) * 768 + k0 + kc * 8);
      *(int4*)(Bs + row * 64 + ((kc ^ (row & 7)) * 8)) = bv;
    }
    __syncthreads();
#pragma unroll
    for (int kk = 0; kk < 2; ++kk) {
      bfrag8 af[4], bf[4];
      const int kc = kk * 4 + (l >> 4);
#pragma unroll
      for (int mi = 0; mi < 4; ++mi) {
        int arow = wm * 64 + mi * 16 + (l & 15);
        af[mi] = *(const bfrag8*)(As + arow * 64 + ((kc ^ (arow & 7)) * 8));
      }
#pragma unroll
      for (int nj = 0; nj < 4; ++nj) {
        int brow = wn * 64 + nj * 16 + (l & 15);
        bf[nj] = *(const bfrag8*)(Bs + brow * 64 + ((kc ^ (brow & 7)) * 8));
      }
#pragma unroll
      for (int mi = 0; mi < 4; ++mi)
#pragma unroll
        for (int nj = 0; nj < 4; ++nj)
          acc[mi][nj] = __builtin_amdgcn_mfma_f32_16x16x32_bf16(af[mi], bf[nj], acc[mi][nj], 0, 0, 0);
    }
  }

  // epilogue: C/D layout col = lane&15, row = (lane>>4)*4 + reg
  const int col = l & 15, rq = l >> 4;
#pragma unroll
  for (int mi = 0; mi < 4; ++mi) {
#pragma unroll
    for (int nj = 0; nj < 4; ++nj) {
      int gn = bn + wn * 64 + nj * 16 + col;
#pragma unroll
      for (int r = 0; r < 4; ++r) {
        int gm = bm + wm * 64 + mi * 16 + rq * 4 + r;
        float val = acc[mi][nj][r];
        if (MODE == 0) {
          val += bias[gn];
          if (gm < M) {
            Cf[(size_t)gm * ldc + gn] = val;
            if (Cb) Cb[(size_t)gm * ldc + gn] = f2bf(val);
          }
        } else {
          val *= iq[gm] * ik[gn];
          Cf[(size_t)gm * ldc + gn] = val;
        }
      }
    }
  }
}

// ---------------- inverse L2 row norms (wave per row) ----------------
__global__ __launch_bounds__(256) void rownorm_kernel(
    const float* __restrict__ X, float* __restrict__ inv, int M) {
  int row = blockIdx.x * 4 + (threadIdx.x >> 6);
  int lane = threadIdx.x & 63;
  if (row >= M) return;
  const float* x = X + (size_t)row * 768;
  float s = 0.f;
  for (int h = lane; h < 768; h += 64) { float v = x[h]; s += v * v; }
#pragma unroll
  for (int m = 1; m < 64; m <<= 1) s += __shfl_xor(s, m);
  if (lane == 0) inv[row] = 1.0f / fmaxf(sqrtf(s), 1e-8f);
}

// ---------------- Sinkhorn per (a,b) 32x32 tile, in-place, + final row L2 norm ----------------
__global__ __launch_bounds__(256) void sinkhorn_kernel(float* __restrict__ C) {
  const int pair = blockIdx.x;
  const int a = pair >> 6, b = pair & 63;
  const int t = threadIdx.x;
  const int i = t >> 3, j0 = (t & 7) << 2;
  const int wave = t >> 6;
  float* base = C + (size_t)(a * 32) * 2048 + b * 32;
  __shared__ float colpart[4][32];
  float4 c4 = *(const float4*)(base + (size_t)i * 2048 + j0);
  float qv[4] = { expf(c4.x * 10.f), expf(c4.y * 10.f), expf(c4.z * 10.f), expf(c4.w * 10.f) };
  for (int it = 0; it < 10; ++it) {
    float rs = qv[0] + qv[1] + qv[2] + qv[3];
    rs += __shfl_xor(rs, 1); rs += __shfl_xor(rs, 2); rs += __shfl_xor(rs, 4);
    float rinv = 1.0f / rs;
#pragma unroll
    for (int u = 0; u < 4; ++u) qv[u] *= rinv;
    float cp[4] = { qv[0], qv[1], qv[2], qv[3] };
#pragma unroll
    for (int m = 8; m < 64; m <<= 1) {
#pragma unroll
      for (int u = 0; u < 4; ++u) cp[u] += __shfl_xor(cp[u], m);
    }
    __syncthreads();
    if ((t & 63) < 8) {
#pragma unroll
      for (int u = 0; u < 4; ++u) colpart[wave][j0 + u] = cp[u];
    }
    __syncthreads();
#pragma unroll
    for (int u = 0; u < 4; ++u) {
      float cs = colpart[0][j0 + u] + colpart[1][j0 + u] + colpart[2][j0 + u] + colpart[3][j0 + u];
      qv[u] /= cs;
    }
  }
  float ss = qv[0] * qv[0] + qv[1] * qv[1] + qv[2] * qv[2] + qv[3] * qv[3];
  ss += __shfl_xor(ss, 1); ss += __shfl_xor(ss, 2); ss += __shfl_xor(ss, 4);
  float tinv = 1.0f / fmaxf(sqrtf(ss), 1e-12f);
  float4 o4 = make_float4(qv[0] * tinv, qv[1] * tinv, qv[2] * tinv, qv[3] * tinv);
  *(float4*)(base + (size_t)i * 2048 + j0) = o4;
}

// ---------------- Fused: attended = T@v + q -> LN1 -> softpool -> LN2 -> scores ----------------
__global__ __launch_bounds__(1024) void attn_pool_kernel(
    const float* __restrict__ T, const float* __restrict__ Vm, const float* __restrict__ Qm,
    const float* __restrict__ ecls, const float* __restrict__ entity_cls,
    const float* __restrict__ mention_cls,
    const float* __restrict__ ln1_g, const float* __restrict__ ln1_b,
    const float* __restrict__ Wsp, const float* __restrict__ bsp,
    const float* __restrict__ ln2_g, const float* __restrict__ ln2_b,
    float* __restrict__ out) {
  const int pair = blockIdx.x;
  const int a = pair >> 6, b = pair & 63;
  const int tid = threadIdx.x;
  const int w = tid >> 6;
  const int r = tid >> 7;
  const int qx = tid & 127;

  __shared__ float Ts[32][33];
  __shared__ float smem[16 * 768];
  __shared__ float red[16][8];
  __shared__ float svals[32];

  {
    int i = tid >> 5, j = tid & 31;
    Ts[i][j] = T[(size_t)(a * 32 + i) * 2048 + b * 32 + j];
  }

  float acc[4][6];
#pragma unroll
  for (int ri = 0; ri < 4; ++ri) {
    const float* qrow = Qm + (size_t)(a * 32 + r + 8 * ri) * 768 + qx * 6;
#pragma unroll
    for (int c = 0; c < 6; ++c) acc[ri][c] = qrow[c];
  }

  for (int ph = 0; ph < 2; ++ph) {
    const int jbase = ph * 16;
    __syncthreads();
#pragma unroll
    for (int u = 0; u < 12; ++u) {
      int e = tid + u * 1024;
      int jj = e / 768, h2 = e - jj * 768;
      smem[e] = Vm[(size_t)(b * 32 + jbase + jj) * 768 + h2];
    }
    __syncthreads();
#pragma unroll
    for (int j = 0; j < 16; ++j) {
      float vv[6];
      const float* vrow = smem + j * 768 + qx * 6;
#pragma unroll
      for (int c = 0; c < 6; ++c) vv[c] = vrow[c];
#pragma unroll
      for (int ri = 0; ri < 4; ++ri) {
        float tj = Ts[r + 8 * ri][jbase + j];
#pragma unroll
        for (int c = 0; c < 6; ++c) acc[ri][c] += tj * vv[c];
      }
    }
  }

  float rsum[4], rsq[4];
#pragma unroll
  for (int ri = 0; ri < 4; ++ri) {
    float s = 0.f, s2 = 0.f;
#pragma unroll
    for (int c = 0; c < 6; ++c) { s += acc[ri][c]; s2 += acc[ri][c] * acc[ri][c]; }
    rsum[ri] = s; rsq[ri] = s2;
  }
#pragma unroll
  for (int m = 1; m < 64; m <<= 1) {
#pragma unroll
    for (int ri = 0; ri < 4; ++ri) { rsum[ri] += __shfl_xor(rsum[ri], m); rsq[ri] += __shfl_xor(rsq[ri], m); }
  }
  if ((tid & 63) == 0) {
#pragma unroll
    for (int ri = 0; ri < 4; ++ri) { red[w][ri] = rsum[ri]; red[w][4 + ri] = rsq[ri]; }
  }
  __syncthreads();
  float mean[4], rstd[4];
#pragma unroll
  for (int ri = 0; ri < 4; ++ri) {
    float s = red[2 * r][ri] + red[2 * r + 1][ri];
    float s2 = red[2 * r][4 + ri] + red[2 * r + 1][4 + ri];
    float m1 = s * (1.0f / 768.0f);
    float var = s2 * (1.0f / 768.0f) - m1 * m1;
    mean[ri] = m1; rstd[ri] = rsqrtf(var + 1e-5f);
  }
  float g1[6], b1[6], wspv[6];
#pragma unroll
  for (int c = 0; c < 6; ++c) {
    g1[c] = ln1_g[qx * 6 + c]; b1[c] = ln1_b[qx * 6 + c]; wspv[c] = Wsp[qx * 6 + c];
  }
#pragma unroll
  for (int ri = 0; ri < 4; ++ri)
#pragma unroll
    for (int c = 0; c < 6; ++c) acc[ri][c] = (acc[ri][c] - mean[ri]) * rstd[ri] * g1[c] + b1[c];

  float sp[4];
#pragma unroll
  for (int ri = 0; ri < 4; ++ri) {
    float s = 0.f;
#pragma unroll
    for (int c = 0; c < 6; ++c) s += acc[ri][c] * wspv[c];
    sp[ri] = s;
  }
#pragma unroll
  for (int m = 1; m < 64; m <<= 1) {
#pragma unroll
    for (int ri = 0; ri < 4; ++ri) sp[ri] += __shfl_xor(sp[ri], m);
  }
  __syncthreads();
  if ((tid & 63) == 0) {
#pragma unroll
    for (int ri = 0; ri < 4; ++ri) red[w][ri] = sp[ri];
  }
  __syncthreads();
  const float bsp0 = bsp[0];
  float sv[4];
#pragma unroll
  for (int ri = 0; ri < 4; ++ri) sv[ri] = red[2 * r][ri] + red[2 * r + 1][ri] + bsp0;
  if (qx == 0) {
#pragma unroll
    for (int ri = 0; ri < 4; ++ri) svals[r + 8 * ri] = sv[ri];
  }
  __syncthreads();
  float mx = -1e30f;
#pragma unroll
  for (int i2 = 0; i2 < 32; ++i2) mx = fmaxf(mx, svals[i2]);
  float se = 0.f;
#pragma unroll
  for (int i2 = 0; i2 < 32; ++i2) se += expf(svals[i2] - mx);
  const float sinv = 1.0f / se;
  float wv[4];
#pragma unroll
  for (int ri = 0; ri < 4; ++ri) wv[ri] = expf(sv[ri] - mx) * sinv;

  float pol[6];
#pragma unroll
  for (int c = 0; c < 6; ++c) {
    float s = 0.f;
#pragma unroll
    for (int ri = 0; ri < 4; ++ri) s += wv[ri] * acc[ri][c];
    pol[c] = s;
  }
  __syncthreads();
#pragma unroll
  for (int c = 0; c < 6; ++c) smem[r * 768 + qx * 6 + c] = pol[c];
  __syncthreads();

  float pooled = 0.f, psum = 0.f, psq = 0.f;
  const int h2 = tid;
  if (tid < 768) {
#pragma unroll
    for (int r2 = 0; r2 < 8; ++r2) pooled += smem[r2 * 768 + h2];
    psum = pooled; psq = pooled * pooled;
  }
#pragma unroll
  for (int m = 1; m < 64; m <<= 1) { psum += __shfl_xor(psum, m); psq += __shfl_xor(psq, m); }
  if ((tid & 63) == 0) { red[w][0] = psum; red[w][1] = psq; }
  __syncthreads();
  float s = 0.f, s2 = 0.f;
#pragma unroll
  for (int w2 = 0; w2 < 16; ++w2) { s += red[w2][0]; s2 += red[w2][1]; }
  const float m2 = s * (1.0f / 768.0f);
  const float var2 = s2 * (1.0f / 768.0f) - m2 * m2;
  const float rs2 = rsqrtf(var2 + 1e-5f);

  float totp = 0.f;
  if (tid < 768) {
    float ctx = (pooled - m2) * rs2 * ln2_g[h2] + ln2_b[h2];
    totp = ctx * ecls[(size_t)a * 768 + h2]
         + mention_cls[(size_t)b * 768 + h2] * entity_cls[(size_t)a * 768 + h2];
  }
  __syncthreads();
#pragma unroll
  for (int m = 1; m < 64; m <<= 1) totp += __shfl_xor(totp, m);
  if ((tid & 63) == 0) red[w][0] = totp;
  __syncthreads();
  if (tid == 0) {
    float t2 = 0.f;
#pragma unroll
    for (int w2 = 0; w2 < 16; ++w2) t2 += red[w2][0];
    out[b * 32 + a] = 0.5f * t2;
  }
}

extern "C" void kernel_launch(void* const* d_in, const int* in_sizes, int n_in,
                              void* d_out, int out_size, void* d_ws, size_t ws_size,
                              hipStream_t stream) {
  const float* entity_cls     = (const float*)d_in[0];
  const float* entity_tokens  = (const float*)d_in[1];
  const float* mention_cls    = (const float*)d_in[2];
  const float* mention_tokens = (const float*)d_in[3];
  const float* Wq = (const float*)d_in[4];   const float* bq = (const float*)d_in[5];
  const float* Wk = (const float*)d_in[6];   const float* bk = (const float*)d_in[7];
  const float* Wv = (const float*)d_in[8];   const float* bv = (const float*)d_in[9];
  const float* ln1_g = (const float*)d_in[10]; const float* ln1_b = (const float*)d_in[11];
  const float* Wcls = (const float*)d_in[12];  const float* bcls = (const float*)d_in[13];
  const float* Wsp = (const float*)d_in[14];   const float* bsp = (const float*)d_in[15];
  const float* ln2_g = (const float*)d_in[16]; const float* ln2_b = (const float*)d_in[17];
  float* out = (float*)d_out;

  // workspace layout
  float* ws = (float*)d_ws;
  float* q    = ws;                         // 1024*768
  float* k    = q + 786432;                 // 2048*768
  float* v    = k + 1572864;                // 2048*768
  float* ecls = v + 1572864;                // 32*768
  float* iq   = ecls + 24576;               // 1024
  float* ik   = iq + 1024;                  // 2048
  unsigned short* qb = (unsigned short*)(ik + 2048);   // 1024*768 bf16
  unsigned short* kb = qb + 786432;                    // 2048*768 bf16
  // union region: phase A (bf16 staging) then C f32 [1024][2048]
  char* R = (char*)(kb + 1572864);
  unsigned short* Ae    = (unsigned short*)R;          // 1024*768
  unsigned short* Am    = Ae + 786432;                 // 2048*768
  unsigned short* Acls  = Am + 1572864;                // 32*768
  unsigned short* WqT   = Acls + 24576;                // 768*768
  unsigned short* WkT   = WqT + 589824;
  unsigned short* WvT   = WkT + 589824;
  unsigned short* WclsT = WvT + 589824;
  float* C = (float*)R;                                // 1024*2048 (aliases phase A; safe: written after)

  dim3 blk(256);
  // bf16 conversions
  cvt_bf16_kernel<<<dim3(768),  blk, 0, stream>>>(entity_tokens,  Ae,   196608);
  cvt_bf16_kernel<<<dim3(1536), blk, 0, stream>>>(mention_tokens, Am,   393216);
  cvt_bf16_kernel<<<dim3(24),   blk, 0, stream>>>(entity_cls,     Acls, 6144);
  transpose_cvt_kernel<<<dim3(24, 24, 4), blk, 0, stream>>>(
      Wq, Wk, Wv, Wcls, WqT, WkT, WvT, WclsT);

  // projections (MFMA bf16): grid (N/128, M/128)
  mfma_gemm_kernel<0><<<dim3(6, 8),  blk, 0, stream>>>(Ae,   WqT,   bq,   nullptr, nullptr, q,    qb,      1024, 768);
  mfma_gemm_kernel<0><<<dim3(6, 16), blk, 0, stream>>>(Am,   WkT,   bk,   nullptr, nullptr, k,    kb,      2048, 768);
  mfma_gemm_kernel<0><<<dim3(6, 16), blk, 0, stream>>>(Am,   WvT,   bv,   nullptr, nullptr, v,    nullptr, 2048, 768);
  mfma_gemm_kernel<0><<<dim3(6, 1),  blk, 0, stream>>>(Acls, WclsT, bcls, nullptr, nullptr, ecls, nullptr, 32,   768);

  rownorm_kernel<<<dim3(256), blk, 0, stream>>>(q, iq, 1024);
  rownorm_kernel<<<dim3(512), blk, 0, stream>>>(k, ik, 2048);

  // cosine GEMM (MFMA bf16): C[1024][2048]
  mfma_gemm_kernel<1><<<dim3(16, 8), blk, 0, stream>>>(qb, kb, nullptr, iq, ik, C, nullptr, 1024, 2048);

  sinkhorn_kernel<<<dim3(2048), blk, 0, stream>>>(C);
  attn_pool_kernel<<<dim3(2048), dim3(1024), 0, stream>>>(
      C, v, q, ecls, entity_cls, mention_cls,
      ln1_g, ln1_b, Wsp, bsp, ln2_g, ln2_b, out);
}

// Round 3
// 217.007 us; speedup vs baseline: 2.7570x; 1.7821x over previous
//
#include <hip/hip_runtime.h>
#include <math.h>

// Shapes (fixed): Na=32, La=32, B=64, Lb=32, Din=H=768.

typedef __attribute__((ext_vector_type(8))) short bfrag8;   // 8 bf16 in 4 VGPRs
typedef __attribute__((ext_vector_type(4))) float f32x4;

__device__ __forceinline__ unsigned short f2bf(float x) {
  union { float f; unsigned u; } v; v.f = x;
  unsigned r = v.u + 0x7fffu + ((v.u >> 16) & 1u);
  return (unsigned short)(r >> 16);
}
__device__ __forceinline__ float bf2f(unsigned short u) {
  union { unsigned u; float f; } v; v.u = ((unsigned)u) << 16; return v.f;
}

// ---------------- f32 -> bf16, 3 tensors in one dispatch ----------------
__global__ __launch_bounds__(256) void cvt_all_kernel(
    const float* __restrict__ a0, const float* __restrict__ a1, const float* __restrict__ a2,
    unsigned short* __restrict__ o0, unsigned short* __restrict__ o1, unsigned short* __restrict__ o2) {
  int bx = blockIdx.x;
  const float* in; unsigned short* out; int i, n4;
  if (bx < 768)       { in = a0; out = o0; i = bx * 256 + threadIdx.x;          n4 = 196608; }
  else if (bx < 2304) { in = a1; out = o1; i = (bx - 768) * 256 + threadIdx.x;  n4 = 393216; }
  else                { in = a2; out = o2; i = (bx - 2304) * 256 + threadIdx.x; n4 = 6144; }
  if (i >= n4) return;
  float4 f = ((const float4*)in)[i];
  ushort4 o;
  o.x = f2bf(f.x); o.y = f2bf(f.y); o.z = f2bf(f.z); o.w = f2bf(f.w);
  ((ushort4*)out)[i] = o;
}

// ---------------- W[768][768] f32 -> WT[768][768] bf16 (transposed), 4 weights ----------------
__global__ __launch_bounds__(256) void transpose_cvt_kernel(
    const float* __restrict__ W0, const float* __restrict__ W1,
    const float* __restrict__ W2, const float* __restrict__ W3,
    unsigned short* __restrict__ O0, unsigned short* __restrict__ O1,
    unsigned short* __restrict__ O2, unsigned short* __restrict__ O3) {
  const int z = blockIdx.z;
  const float* W = (z == 0) ? W0 : (z == 1) ? W1 : (z == 2) ? W2 : W3;
  unsigned short* O = (z == 0) ? O0 : (z == 1) ? O1 : (z == 2) ? O2 : O3;
  __shared__ float t[32][33];
  const int bx = blockIdx.x * 32, by = blockIdx.y * 32;
  const int tx = threadIdx.x & 31, ty = threadIdx.x >> 5;
#pragma unroll
  for (int u = 0; u < 4; ++u) {
    int row = ty + u * 8;
    t[row][tx] = W[(size_t)(by + row) * 768 + bx + tx];
  }
  __syncthreads();
#pragma unroll
  for (int u = 0; u < 4; ++u) {
    int row = ty + u * 8;
    O[(size_t)(bx + row) * 768 + by + tx] = f2bf(t[tx][row]);
  }
}

// ---------------- merged projection GEMMs: z=0:q->qb, 1:k->kb, 2:v->vT, 3:ecls(f32) ----------------
// C[M][768] = A[M][768] @ B[768][768]^T + bias ; tile 128x128, BK=64, 16x16x32 bf16 MFMA
__global__ __launch_bounds__(256) void proj_gemm_kernel(
    const unsigned short* __restrict__ Ae, const unsigned short* __restrict__ Am,
    const unsigned short* __restrict__ Acls,
    const unsigned short* __restrict__ WqT, const unsigned short* __restrict__ WkT,
    const unsigned short* __restrict__ WvT, const unsigned short* __restrict__ WclsT,
    const float* __restrict__ bq, const float* __restrict__ bk,
    const float* __restrict__ bv, const float* __restrict__ bcls,
    unsigned short* __restrict__ qb, unsigned short* __restrict__ kb,
    unsigned short* __restrict__ vT, float* __restrict__ ecls) {
  const int z = blockIdx.z;
  const int M = (z == 0) ? 1024 : (z == 3) ? 32 : 2048;
  const int bm = blockIdx.y * 128;
  if (bm >= M) return;
  const unsigned short* A = (z == 3) ? Acls : (z == 0) ? Ae : Am;
  const unsigned short* B = (z == 0) ? WqT : (z == 1) ? WkT : (z == 2) ? WvT : WclsT;
  const float* bias = (z == 0) ? bq : (z == 1) ? bk : (z == 2) ? bv : bcls;

  __shared__ unsigned short As[128 * 64];
  __shared__ unsigned short Bs[128 * 64];
  const int t = threadIdx.x;
  const int bn = blockIdx.x * 128;
  const int l = t & 63, w = t >> 6;
  const int wm = w & 1, wn = w >> 1;

  f32x4 acc[4][4];
#pragma unroll
  for (int mi = 0; mi < 4; ++mi)
#pragma unroll
    for (int nj = 0; nj < 4; ++nj) { f32x4 zz = {0.f, 0.f, 0.f, 0.f}; acc[mi][nj] = zz; }

  for (int k0 = 0; k0 < 768; k0 += 64) {
    __syncthreads();
#pragma unroll
    for (int u = 0; u < 4; ++u) {
      int c = t + u * 256;
      int row = c >> 3, kc = c & 7;
      int gm = bm + row; gm = gm < M ? gm : M - 1;
      int4 av = *(const int4*)(A + (size_t)gm * 768 + k0 + kc * 8);
      *(int4*)(As + row * 64 + ((kc ^ (row & 7)) * 8)) = av;
      int4 bv4 = *(const int4*)(B + (size_t)(bn + row) * 768 + k0 + kc * 8);
      *(int4*)(Bs + row * 64 + ((kc ^ (row & 7)) * 8)) = bv4;
    }
    __syncthreads();
#pragma unroll
    for (int kk = 0; kk < 2; ++kk) {
      bfrag8 af[4], bf[4];
      const int kc = kk * 4 + (l >> 4);
#pragma unroll
      for (int mi = 0; mi < 4; ++mi) {
        int arow = wm * 64 + mi * 16 + (l & 15);
        af[mi] = *(const bfrag8*)(As + arow * 64 + ((kc ^ (arow & 7)) * 8));
      }
#pragma unroll
      for (int nj = 0; nj < 4; ++nj) {
        int brow = wn * 64 + nj * 16 + (l & 15);
        bf[nj] = *(const bfrag8*)(Bs + brow * 64 + ((kc ^ (brow & 7)) * 8));
      }
#pragma unroll
      for (int mi = 0; mi < 4; ++mi)
#pragma unroll
        for (int nj = 0; nj < 4; ++nj)
          acc[mi][nj] = __builtin_amdgcn_mfma_f32_16x16x32_bf16(af[mi], bf[nj], acc[mi][nj], 0, 0, 0);
    }
  }

  const int col = l & 15, rq = l >> 4;
#pragma unroll
  for (int mi = 0; mi < 4; ++mi) {
#pragma unroll
    for (int nj = 0; nj < 4; ++nj) {
      int gn = bn + wn * 64 + nj * 16 + col;
      float bs = bias[gn];
#pragma unroll
      for (int r = 0; r < 4; ++r) {
        int gm = bm + wm * 64 + mi * 16 + rq * 4 + r;
        if (gm >= M) continue;
        float val = acc[mi][nj][r] + bs;
        if (z == 0)      qb[(size_t)gm * 768 + gn] = f2bf(val);
        else if (z == 1) kb[(size_t)gm * 768 + gn] = f2bf(val);
        else if (z == 2) {
          int bb = gm >> 5, j = gm & 31;
          vT[((size_t)bb * 768 + gn) * 32 + j] = f2bf(val);
        } else           ecls[(size_t)gm * 768 + gn] = val;
      }
    }
  }
}

// ---------------- inverse L2 row norms from bf16 (wave per row; rows 0..1023 -> iq, rest -> ik) ----
__global__ __launch_bounds__(256) void rownorm_bf16_kernel(
    const unsigned short* __restrict__ qb, const unsigned short* __restrict__ kb,
    float* __restrict__ iq, float* __restrict__ ik) {
  int row = blockIdx.x * 4 + (threadIdx.x >> 6);
  int lane = threadIdx.x & 63;
  const unsigned short* src; float* dst;
  if (row < 1024) { src = qb + (size_t)row * 768; dst = iq + row; }
  else            { src = kb + (size_t)(row - 1024) * 768; dst = ik + (row - 1024); }
  const unsigned short* p = src + lane * 12;
  float s = 0.f;
#pragma unroll
  for (int u = 0; u < 3; ++u) {
    ushort4 u4 = *(const ushort4*)(p + u * 4);
    float x0 = bf2f(u4.x), x1 = bf2f(u4.y), x2 = bf2f(u4.z), x3 = bf2f(u4.w);
    s += x0 * x0 + x1 * x1 + x2 * x2 + x3 * x3;
  }
#pragma unroll
  for (int m = 1; m < 64; m <<= 1) s += __shfl_xor(s, m);
  if (lane == 0) *dst = 1.0f / fmaxf(sqrtf(s), 1e-8f);
}

// ---------------- cosine GEMM: C[1024][2048] = (qb @ kb^T) * iq * ik ----------------
__global__ __launch_bounds__(256) void cos_mfma_kernel(
    const unsigned short* __restrict__ A, const unsigned short* __restrict__ B,
    const float* __restrict__ iq, const float* __restrict__ ik, float* __restrict__ C) {
  __shared__ unsigned short As[128 * 64];
  __shared__ unsigned short Bs[128 * 64];
  const int t = threadIdx.x;
  const int bn = blockIdx.x * 128, bm = blockIdx.y * 128;
  const int l = t & 63, w = t >> 6;
  const int wm = w & 1, wn = w >> 1;

  f32x4 acc[4][4];
#pragma unroll
  for (int mi = 0; mi < 4; ++mi)
#pragma unroll
    for (int nj = 0; nj < 4; ++nj) { f32x4 zz = {0.f, 0.f, 0.f, 0.f}; acc[mi][nj] = zz; }

  for (int k0 = 0; k0 < 768; k0 += 64) {
    __syncthreads();
#pragma unroll
    for (int u = 0; u < 4; ++u) {
      int c = t + u * 256;
      int row = c >> 3, kc = c & 7;
      int4 av = *(const int4*)(A + (size_t)(bm + row) * 768 + k0 + kc * 8);
      *(int4*)(As + row * 64 + ((kc ^ (row & 7)) * 8)) = av;
      int4 bv4 = *(const int4*)(B + (size_t)(bn + row) * 768 + k0 + kc * 8);
      *(int4*)(Bs + row * 64 + ((kc ^ (row & 7)) * 8)) = bv4;
    }
    __syncthreads();
#pragma unroll
    for (int kk = 0; kk < 2; ++kk) {
      bfrag8 af[4], bf[4];
      const int kc = kk * 4 + (l >> 4);
#pragma unroll
      for (int mi = 0; mi < 4; ++mi) {
        int arow = wm * 64 + mi * 16 + (l & 15);
        af[mi] = *(const bfrag8*)(As + arow * 64 + ((kc ^ (arow & 7)) * 8));
      }
#pragma unroll
      for (int nj = 0; nj < 4; ++nj) {
        int brow = wn * 64 + nj * 16 + (l & 15);
        bf[nj] = *(const bfrag8*)(Bs + brow * 64 + ((kc ^ (brow & 7)) * 8));
      }
#pragma unroll
      for (int mi = 0; mi < 4; ++mi)
#pragma unroll
        for (int nj = 0; nj < 4; ++nj)
          acc[mi][nj] = __builtin_amdgcn_mfma_f32_16x16x32_bf16(af[mi], bf[nj], acc[mi][nj], 0, 0, 0);
    }
  }

  const int col = l & 15, rq = l >> 4;
#pragma unroll
  for (int mi = 0; mi < 4; ++mi) {
#pragma unroll
    for (int nj = 0; nj < 4; ++nj) {
      int gn = bn + wn * 64 + nj * 16 + col;
      float kn = ik[gn];
#pragma unroll
      for (int r = 0; r < 4; ++r) {
        int gm = bm + wm * 64 + mi * 16 + rq * 4 + r;
        C[(size_t)gm * 2048 + gn] = acc[mi][nj][r] * iq[gm] * kn;
      }
    }
  }
}

// ---------------- Sinkhorn per (a,b) 32x32 tile, in-place, + final row L2 norm ----------------
__global__ __launch_bounds__(256) void sinkhorn_kernel(float* __restrict__ C) {
  const int pair = blockIdx.x;
  const int a = pair >> 6, b = pair & 63;
  const int t = threadIdx.x;
  const int i = t >> 3, j0 = (t & 7) << 2;
  const int wave = t >> 6;
  float* base = C + (size_t)(a * 32) * 2048 + b * 32;
  __shared__ float colpart[4][32];
  float4 c4 = *(const float4*)(base + (size_t)i * 2048 + j0);
  float qv[4] = { expf(c4.x * 10.f), expf(c4.y * 10.f), expf(c4.z * 10.f), expf(c4.w * 10.f) };
  for (int it = 0; it < 10; ++it) {
    float rs = qv[0] + qv[1] + qv[2] + qv[3];
    rs += __shfl_xor(rs, 1); rs += __shfl_xor(rs, 2); rs += __shfl_xor(rs, 4);
    float rinv = 1.0f / rs;
#pragma unroll
    for (int u = 0; u < 4; ++u) qv[u] *= rinv;
    float cp[4] = { qv[0], qv[1], qv[2], qv[3] };
#pragma unroll
    for (int m = 8; m < 64; m <<= 1) {
#pragma unroll
      for (int u = 0; u < 4; ++u) cp[u] += __shfl_xor(cp[u], m);
    }
    __syncthreads();
    if ((t & 63) < 8) {
#pragma unroll
      for (int u = 0; u < 4; ++u) colpart[wave][j0 + u] = cp[u];
    }
    __syncthreads();
#pragma unroll
    for (int u = 0; u < 4; ++u) {
      float cs = colpart[0][j0 + u] + colpart[1][j0 + u] + colpart[2][j0 + u] + colpart[3][j0 + u];
      qv[u] /= cs;
    }
  }
  float ss = qv[0] * qv[0] + qv[1] * qv[1] + qv[2] * qv[2] + qv[3] * qv[3];
  ss += __shfl_xor(ss, 1); ss += __shfl_xor(ss, 2); ss += __shfl_xor(ss, 4);
  float tinv = 1.0f / fmaxf(sqrtf(ss), 1e-12f);
  float4 o4 = make_float4(qv[0] * tinv, qv[1] * tinv, qv[2] * tinv, qv[3] * tinv);
  *(float4*)(base + (size_t)i * 2048 + j0) = o4;
}

// ---------------- Fused MFMA attn: attended = T@v + q -> LN1 -> softpool -> LN2 -> scores ------
// One 256-thread block per (b,a) pair. Wave w owns cols [w*192,(w+1)*192).
// MFMA 16x16x32: D row = (l>>4)*4+reg (attended row i), D col = l&15 (h within 16-tile).
__global__ __launch_bounds__(256) void attn_mfma_kernel(
    const float* __restrict__ T,            // [1024][2048] f32 post-sinkhorn
    const unsigned short* __restrict__ vT,  // [64][768][32] bf16: vT[b][h][j] = v[b*32+j][h]
    const unsigned short* __restrict__ qb,  // [1024][768] bf16
    const float* __restrict__ ecls,
    const float* __restrict__ entity_cls, const float* __restrict__ mention_cls,
    const float* __restrict__ ln1_g, const float* __restrict__ ln1_b,
    const float* __restrict__ Wsp, const float* __restrict__ bsp,
    const float* __restrict__ ln2_g, const float* __restrict__ ln2_b,
    float* __restrict__ out) {
  const int pair = blockIdx.x;
  const int b = pair >> 5, a = pair & 31;
  const int t = threadIdx.x;
  const int w = t >> 6, l = t & 63;
  const int cg = l & 15, rq = l >> 4;

  __shared__ float Ts[32][34];           // +2 pad: frag reads land 2-way (free)
  __shared__ float redA[4][32], redB[4][32];
  __shared__ float svals[32];
  __shared__ float red2[4][2];
  __shared__ float red3[4];

  { // load T tile, coalesced
    int i = t >> 3, j0 = (t & 7) * 4;
    const float* src = T + (size_t)(a * 32 + i) * 2048 + b * 32 + j0;
    float4 v4 = *(const float4*)src;
    Ts[i][j0] = v4.x; Ts[i][j0 + 1] = v4.y; Ts[i][j0 + 2] = v4.z; Ts[i][j0 + 3] = v4.w;
  }
  __syncthreads();

  // A fragments: af[mi] = T[mi*16+cg][rq*8 .. +7] as bf16
  bfrag8 af[2];
#pragma unroll
  for (int mi = 0; mi < 2; ++mi) {
    const float* p = &Ts[mi * 16 + cg][rq * 8];
    bfrag8 f;
#pragma unroll
    for (int u = 0; u < 8; ++u) f[u] = (short)f2bf(p[u]);
    af[mi] = f;
  }

  // MFMA with q residual as C operand
  f32x4 acc[2][12];
  const unsigned short* vTb = vT + (size_t)b * 768 * 32;
  const unsigned short* qba = qb + (size_t)(a * 32) * 768;
#pragma unroll
  for (int nj = 0; nj < 12; ++nj) {
    int h = w * 192 + nj * 16 + cg;
    bfrag8 bf = *(const bfrag8*)(vTb + (size_t)h * 32 + rq * 8);
#pragma unroll
    for (int mi = 0; mi < 2; ++mi) {
      f32x4 ci;
#pragma unroll
      for (int r = 0; r < 4; ++r)
        ci[r] = bf2f(qba[(size_t)(mi * 16 + rq * 4 + r) * 768 + h]);
      acc[mi][nj] = __builtin_amdgcn_mfma_f32_16x16x32_bf16(af[mi], bf, ci, 0, 0, 0);
    }
  }

  // ---- LN1 stats per attended row ----
  float s1[2][4], s2[2][4];
#pragma unroll
  for (int mi = 0; mi < 2; ++mi)
#pragma unroll
    for (int r = 0; r < 4; ++r) {
      float s = 0.f, q2 = 0.f;
#pragma unroll
      for (int nj = 0; nj < 12; ++nj) { float x = acc[mi][nj][r]; s += x; q2 += x * x; }
      s1[mi][r] = s; s2[mi][r] = q2;
    }
#pragma unroll
  for (int m = 1; m < 16; m <<= 1) {
#pragma unroll
    for (int mi = 0; mi < 2; ++mi)
#pragma unroll
      for (int r = 0; r < 4; ++r) {
        s1[mi][r] += __shfl_xor(s1[mi][r], m);
        s2[mi][r] += __shfl_xor(s2[mi][r], m);
      }
  }
  if (cg == 0) {
#pragma unroll
    for (int mi = 0; mi < 2; ++mi)
#pragma unroll
      for (int r = 0; r < 4; ++r) {
        int row = mi * 16 + rq * 4 + r;
        redA[w][row] = s1[mi][r]; redB[w][row] = s2[mi][r];
      }
  }
  __syncthreads();
  float mean[2][4], rstd[2][4];
#pragma unroll
  for (int mi = 0; mi < 2; ++mi)
#pragma unroll
    for (int r = 0; r < 4; ++r) {
      int row = mi * 16 + rq * 4 + r;
      float s = redA[0][row] + redA[1][row] + redA[2][row] + redA[3][row];
      float q2 = redB[0][row] + redB[1][row] + redB[2][row] + redB[3][row];
      float m1 = s * (1.0f / 768.0f);
      float var = q2 * (1.0f / 768.0f) - m1 * m1;
      mean[mi][r] = m1; rstd[mi][r] = rsqrtf(var + 1e-5f);
    }

  // ---- apply LN1, softpool logits ----
  float sp[2][4] = {};
#pragma unroll
  for (int nj = 0; nj < 12; ++nj) {
    int h = w * 192 + nj * 16 + cg;
    float g1 = ln1_g[h], b1 = ln1_b[h], ws = Wsp[h];
#pragma unroll
    for (int mi = 0; mi < 2; ++mi)
#pragma unroll
      for (int r = 0; r < 4; ++r) {
        float x = (acc[mi][nj][r] - mean[mi][r]) * rstd[mi][r] * g1 + b1;
        acc[mi][nj][r] = x;
        sp[mi][r] += x * ws;
      }
  }
#pragma unroll
  for (int m = 1; m < 16; m <<= 1) {
#pragma unroll
    for (int mi = 0; mi < 2; ++mi)
#pragma unroll
      for (int r = 0; r < 4; ++r) sp[mi][r] += __shfl_xor(sp[mi][r], m);
  }
  __syncthreads();            // redA readers done
  if (cg == 0) {
#pragma unroll
    for (int mi = 0; mi < 2; ++mi)
#pragma unroll
      for (int r = 0; r < 4; ++r) redA[w][mi * 16 + rq * 4 + r] = sp[mi][r];
  }
  __syncthreads();
  if (t < 32) svals[t] = redA[0][t] + redA[1][t] + redA[2][t] + redA[3][t] + bsp[0];
  __syncthreads();
  float mx = -1e30f;
#pragma unroll
  for (int i2 = 0; i2 < 32; ++i2) mx = fmaxf(mx, svals[i2]);
  float se = 0.f;
#pragma unroll
  for (int i2 = 0; i2 < 32; ++i2) se += expf(svals[i2] - mx);
  const float sinv = 1.0f / se;
  float wv[2][4];
#pragma unroll
  for (int mi = 0; mi < 2; ++mi)
#pragma unroll
    for (int r = 0; r < 4; ++r)
      wv[mi][r] = expf(svals[mi * 16 + rq * 4 + r] - mx) * sinv;

  // ---- pooled[h]: weighted sum over 32 rows ----
  float pol[12];
#pragma unroll
  for (int nj = 0; nj < 12; ++nj) {
    float s = 0.f;
#pragma unroll
    for (int mi = 0; mi < 2; ++mi)
#pragma unroll
      for (int r = 0; r < 4; ++r) s += wv[mi][r] * acc[mi][nj][r];
    pol[nj] = s;
  }
#pragma unroll
  for (int nj = 0; nj < 12; ++nj) {
    pol[nj] += __shfl_xor(pol[nj], 16);
    pol[nj] += __shfl_xor(pol[nj], 32);
  }
  // now each lane holds pooled for its 12 cols (replicated x4 across rq)

  // ---- LN2 stats over 768 cols ----
  float ps = 0.f, pq = 0.f;
#pragma unroll
  for (int nj = 0; nj < 12; ++nj) { ps += pol[nj]; pq += pol[nj] * pol[nj]; }
#pragma unroll
  for (int m = 1; m < 64; m <<= 1) { ps += __shfl_xor(ps, m); pq += __shfl_xor(pq, m); }
  if (l == 0) { red2[w][0] = ps; red2[w][1] = pq; }
  __syncthreads();
  {
    float s = red2[0][0] + red2[1][0] + red2[2][0] + red2[3][0];
    float q2 = red2[0][1] + red2[1][1] + red2[2][1] + red2[3][1];
    const float inv = 1.0f / (4.0f * 768.0f);     // x4 replication
    float m2 = s * inv;
    float var2 = q2 * inv - m2 * m2;
    float rs2 = rsqrtf(var2 + 1e-5f);

    // ---- final scores: g2l + g2g ----
    const float* ea = entity_cls + (size_t)a * 768;
    const float* mb = mention_cls + (size_t)b * 768;
    const float* ec = ecls + (size_t)a * 768;
    float tot = 0.f;
#pragma unroll
    for (int nj = 0; nj < 12; ++nj) {
      int h = w * 192 + nj * 16 + cg;
      float ctx = (pol[nj] - m2) * rs2 * ln2_g[h] + ln2_b[h];
      tot += ctx * ec[h] + mb[h] * ea[h];
    }
#pragma unroll
    for (int m = 1; m < 64; m <<= 1) tot += __shfl_xor(tot, m);
    if (l == 0) red3[w] = tot;
  }
  __syncthreads();
  if (t == 0) {
    float g = red3[0] + red3[1] + red3[2] + red3[3];
    out[b * 32 + a] = 0.5f * 0.25f * g;   // 0.25: x4 rq replication
  }
}

extern "C" void kernel_launch(void* const* d_in, const int* in_sizes, int n_in,
                              void* d_out, int out_size, void* d_ws, size_t ws_size,
                              hipStream_t stream) {
  const float* entity_cls     = (const float*)d_in[0];
  const float* entity_tokens  = (const float*)d_in[1];
  const float* mention_cls    = (const float*)d_in[2];
  const float* mention_tokens = (const float*)d_in[3];
  const float* Wq = (const float*)d_in[4];   const float* bq = (const float*)d_in[5];
  const float* Wk = (const float*)d_in[6];   const float* bk = (const float*)d_in[7];
  const float* Wv = (const float*)d_in[8];   const float* bv = (const float*)d_in[9];
  const float* ln1_g = (const float*)d_in[10]; const float* ln1_b = (const float*)d_in[11];
  const float* Wcls = (const float*)d_in[12];  const float* bcls = (const float*)d_in[13];
  const float* Wsp = (const float*)d_in[14];   const float* bsp = (const float*)d_in[15];
  const float* ln2_g = (const float*)d_in[16]; const float* ln2_b = (const float*)d_in[17];
  float* out = (float*)d_out;

  // workspace layout (floats)
  float* ws   = (float*)d_ws;
  float* ecls = ws;                          // 32*768
  float* iq   = ecls + 24576;                // 1024
  float* ik   = iq + 1024;                   // 2048
  unsigned short* qb = (unsigned short*)(ik + 2048);  // 1024*768 bf16
  unsigned short* kb = qb + 786432;                   // 2048*768 bf16
  unsigned short* vT = kb + 1572864;                  // 64*768*32 bf16
  // union region: phase A staging, then C f32 [1024][2048]
  char* R = (char*)(vT + 1572864);
  unsigned short* Ae    = (unsigned short*)R;         // 1024*768
  unsigned short* Am    = Ae + 786432;                // 2048*768
  unsigned short* Acls  = Am + 1572864;               // 32*768
  unsigned short* WqT   = Acls + 24576;               // 768*768 x4
  unsigned short* WkT   = WqT + 589824;
  unsigned short* WvT   = WkT + 589824;
  unsigned short* WclsT = WvT + 589824;
  float* C = (float*)R;                               // 1024*2048 (aliases staging; written after)

  dim3 blk(256);
  cvt_all_kernel<<<dim3(2328), blk, 0, stream>>>(
      entity_tokens, mention_tokens, entity_cls, Ae, Am, Acls);
  transpose_cvt_kernel<<<dim3(24, 24, 4), blk, 0, stream>>>(
      Wq, Wk, Wv, Wcls, WqT, WkT, WvT, WclsT);
  proj_gemm_kernel<<<dim3(6, 16, 4), blk, 0, stream>>>(
      Ae, Am, Acls, WqT, WkT, WvT, WclsT, bq, bk, bv, bcls, qb, kb, vT, ecls);
  rownorm_bf16_kernel<<<dim3(768), blk, 0, stream>>>(qb, kb, iq, ik);
  cos_mfma_kernel<<<dim3(16, 8), blk, 0, stream>>>(qb, kb, iq, ik, C);
  sinkhorn_kernel<<<dim3(2048), blk, 0, stream>>>(C);
  attn_mfma_kernel<<<dim3(2048), blk, 0, stream>>>(
      C, vT, qb, ecls, entity_cls, mention_cls,
      ln1_g, ln1_b, Wsp, bsp, ln2_g, ln2_b, out);
}